// Round 1
// baseline (511.320 us; speedup 1.0000x reference)
//
#include <hip/hip_runtime.h>
#include <math.h>

#define BB 4
#define C 64
#define O 64
#define H 128
#define W 128
#define OG 2
#define Cg 32
#define K2 9
#define HW (H*W)
#define NOFF 36   /* 2*OG*K2 offset channels */
#define NMSK 18   /* OG*K2 mask channels */
#define NC 54     /* NOFF+NMSK */

// ---------------------------------------------------------------------------
// Weight re-layout:
//  wcomb[c][tap][j] (j<36: offset conv weights, j>=36: mask conv weights)
//    -> inner oc-loop reads 54 contiguous floats at uniform address (s_load)
//  wt[g][k][c][o] -> inner o-loop reads 64 contiguous floats at uniform addr
// ---------------------------------------------------------------------------
__global__ __launch_bounds__(256) void prep_weights(
    const float* __restrict__ w_main, const float* __restrict__ w_off,
    const float* __restrict__ w_mask, float* __restrict__ wcomb,
    float* __restrict__ wt) {
  int i = blockIdx.x * 256 + threadIdx.x;
  const int NW1 = C * K2 * NC;        // 31104
  const int NW2 = OG * K2 * Cg * O;   // 36864
  if (i < NW1) {
    int j = i % NC;
    int ct = i / NC;
    int tap = ct % K2;
    int c = ct / K2;
    float v = (j < NOFF) ? w_off[(j * C + c) * K2 + tap]
                         : w_mask[((j - NOFF) * C + c) * K2 + tap];
    wcomb[i] = v;
  } else if (i < NW1 + NW2) {
    int t = i - NW1;
    int o = t % O;
    int r = t / O;           // r = (g*9+k)*32 + c
    int c = r % Cg;
    int gk = r / Cg;         // g*9+k
    int g = gk / K2;
    int k = gk % K2;
    wt[t] = w_main[(o * C + g * Cg + c) * K2 + k];
  }
}

// ---------------------------------------------------------------------------
// Offset/mask 3x3 conv (54 output channels), thread-per-pixel.
// Tile: 64 wide x 4 tall per 256-thread block; grid = 4*32*2 = 256 blocks.
// ---------------------------------------------------------------------------
__global__ __launch_bounds__(256) void conv_offmask(
    const float* __restrict__ x, const float* __restrict__ wcomb,
    const float* __restrict__ b_off, const float* __restrict__ b_mask,
    float* __restrict__ offs, float* __restrict__ msk) {
  int lane = threadIdx.x;
  int w = (blockIdx.x & 1) * 64 + (lane & 63);
  int h = ((blockIdx.x >> 1) & 31) * 4 + (lane >> 6);
  int b = blockIdx.x >> 6;

  float acc[NC];
#pragma unroll
  for (int j = 0; j < NC; j++) acc[j] = 0.f;

  const float* xb = x + b * C * HW;
#pragma unroll 1
  for (int c = 0; c < C; c++) {
    const float* xc = xb + c * HW;
    float xv[9];
#pragma unroll
    for (int dy = 0; dy < 3; dy++) {
      int yy = h + dy - 1;
      bool yok = (unsigned)yy < (unsigned)H;
#pragma unroll
      for (int dx = 0; dx < 3; dx++) {
        int xx = w + dx - 1;
        bool ok = yok && ((unsigned)xx < (unsigned)W);
        xv[dy * 3 + dx] = ok ? xc[yy * W + xx] : 0.f;
      }
    }
    const float* wr = wcomb + c * K2 * NC;
#pragma unroll
    for (int t = 0; t < 9; t++) {
#pragma unroll
      for (int j = 0; j < NC; j++) acc[j] += xv[t] * wr[t * NC + j];
    }
  }

  int pix = h * W + w;
#pragma unroll
  for (int j = 0; j < NOFF; j++)
    offs[(b * NOFF + j) * HW + pix] = acc[j] + b_off[j];
#pragma unroll
  for (int j = 0; j < NMSK; j++) {
    float v = acc[NOFF + j] + b_mask[j];
    msk[(b * NMSK + j) * HW + pix] = 1.f / (1.f + __expf(-v));
  }
}

// ---------------------------------------------------------------------------
// Deformable conv main kernel, thread-per-pixel, 64 output channels in regs.
// ---------------------------------------------------------------------------
__global__ __launch_bounds__(256) void deform(
    const float* __restrict__ x, const float* __restrict__ wt,
    const float* __restrict__ offs, const float* __restrict__ msk,
    float* __restrict__ out) {
  int lane = threadIdx.x;
  int w = (blockIdx.x & 1) * 64 + (lane & 63);
  int h = ((blockIdx.x >> 1) & 31) * 4 + (lane >> 6);
  int b = blockIdx.x >> 6;
  int pix = h * W + w;

  float acc[O];
#pragma unroll
  for (int o = 0; o < O; o++) acc[o] = 0.f;

#pragma unroll 1
  for (int g = 0; g < OG; g++) {
    const float* xg = x + (b * C + g * Cg) * HW;
#pragma unroll 1
    for (int k = 0; k < K2; k++) {
      int gk = g * K2 + k;
      float offy = offs[(b * NOFF + gk * 2) * HW + pix];
      float offx = offs[(b * NOFF + gk * 2 + 1) * HW + pix];
      float m = msk[(b * NMSK + gk) * HW + pix];

      float py = offy + (float)(h - 1 + k / 3);
      float px = offx + (float)(w - 1 + k % 3);
      float y0f = floorf(py), x0f = floorf(px);
      float wy1 = py - y0f, wx1 = px - x0f;
      float wy0 = 1.f - wy1, wx0 = 1.f - wx1;
      int y0 = (int)y0f, x0 = (int)x0f;
      int y1 = y0 + 1, x1 = x0 + 1;
      bool y0ok = (unsigned)y0 < (unsigned)H, y1ok = (unsigned)y1 < (unsigned)H;
      bool x0ok = (unsigned)x0 < (unsigned)W, x1ok = (unsigned)x1 < (unsigned)W;
      // fold validity and mask into the 4 corner weights (once per (g,k))
      float w00 = (y0ok && x0ok) ? wy0 * wx0 * m : 0.f;
      float w01 = (y0ok && x1ok) ? wy0 * wx1 * m : 0.f;
      float w10 = (y1ok && x0ok) ? wy1 * wx0 * m : 0.f;
      float w11 = (y1ok && x1ok) ? wy1 * wx1 * m : 0.f;
      int y0c = min(max(y0, 0), H - 1), y1c = min(max(y1, 0), H - 1);
      int x0c = min(max(x0, 0), W - 1), x1c = min(max(x1, 0), W - 1);
      const float* p00 = xg + y0c * W + x0c;
      const float* p01 = xg + y0c * W + x1c;
      const float* p10 = xg + y1c * W + x0c;
      const float* p11 = xg + y1c * W + x1c;
      const float* wrow = wt + gk * Cg * O;
#pragma unroll 2
      for (int c = 0; c < Cg; c++) {
        float v = p00[c * HW] * w00 + p01[c * HW] * w01 +
                  p10[c * HW] * w10 + p11[c * HW] * w11;
        const float* wr = wrow + c * O;
#pragma unroll
        for (int o = 0; o < O; o++) acc[o] += v * wr[o];
      }
    }
  }

  float* ob = out + b * O * HW + pix;
#pragma unroll
  for (int o = 0; o < O; o++) ob[o * HW] = acc[o];
}

// ---------------------------------------------------------------------------
extern "C" void kernel_launch(void* const* d_in, const int* in_sizes, int n_in,
                              void* d_out, int out_size, void* d_ws,
                              size_t ws_size, hipStream_t stream) {
  const float* x = (const float*)d_in[0];
  const float* w_main = (const float*)d_in[1];
  const float* w_off = (const float*)d_in[2];
  const float* b_off = (const float*)d_in[3];
  const float* w_mask = (const float*)d_in[4];
  const float* b_mask = (const float*)d_in[5];
  float* out = (float*)d_out;

  float* offs = (float*)d_ws;                 // B*36*HW floats
  float* msk = offs + BB * NOFF * HW;         // B*18*HW floats
  float* wcomb = msk + BB * NMSK * HW;        // 31104 floats
  float* wt = wcomb + C * K2 * NC;            // 36864 floats

  const int nprep = C * K2 * NC + OG * K2 * Cg * O;  // 67968
  prep_weights<<<(nprep + 255) / 256, 256, 0, stream>>>(w_main, w_off, w_mask,
                                                        wcomb, wt);
  conv_offmask<<<256, 256, 0, stream>>>(x, wcomb, b_off, b_mask, offs, msk);
  deform<<<256, 256, 0, stream>>>(x, wt, offs, msk, out);
}